// Round 4
// baseline (382.985 us; speedup 1.0000x reference)
//
#include <hip/hip_runtime.h>

// GradientConsistencyLoss on f[2,3,192,192,192] fp32.
// loss = 0.1 * ( mean(div^2) + mean(sqrt(cx^2+cy^2+cz^2+1e-8)) )
// jnp.gradient semantics: central interior, one-sided edges, unit spacing.
//
// R4: LDS plane-staging. R3 (~73us kernel) stayed latency-bound: every
// thread re-loaded h+-1 rows (3.2x L1 amplification) and the register
// pipeline forced per-iter partial vmcnt drains. Now a block stages one
// plane (3ch) in LDS: per step each thread loads ONLY its center float4
// (plane d+2, used 2 barrier-steps later); h/w neighbors come from LDS,
// d+-1 from rolling registers. vmem instrs/thread-step: 15 -> 3.

#define DEP 192
#define HGT 192
#define WID 192
#define NB  2

constexpr int SD = HGT * WID;          // d-stride (floats)
constexpr int SC = DEP * SD;           // channel stride
constexpr int SB = 3 * SC;             // batch stride
constexpr int TH   = 16;               // tile rows (h)
constexpr int TW4  = 16;               // tile float4-cols
constexpr int TW   = TW4 * 4;          // 64 floats of w per tile
constexpr int DSEG = 12;               // planes marched per block
constexpr int NDS  = DEP / DSEG;       // 16
constexpr int NHB  = HGT / TH;         // 12
constexpr int NWB  = WID / TW;         // 3
constexpr int NBLK = NB * NDS * NHB * NWB;  // 1152 blocks
constexpr int ROWF = (TW4 + 1) * 4;    // LDS row stride: 68 floats (+4 bank skew)
constexpr float SCALE = (float)(0.1 / (double)((long long)NB * DEP * HGT * WID));
constexpr float EPS_C = 1e-8f;

struct V4 { float v[4]; };
__device__ __forceinline__ V4 ld4(const float* p) {
    const float4 t = *(const float4*)p;
    V4 r; r.v[0] = t.x; r.v[1] = t.y; r.v[2] = t.z; r.v[3] = t.w; return r;
}
__device__ __forceinline__ void st4(float* p, const V4& a) {
    *(float4*)p = make_float4(a.v[0], a.v[1], a.v[2], a.v[3]);
}
__device__ __forceinline__ V4 ld4s(const float* p) {   // LDS b128 read
    const float4 t = *(const float4*)p;
    V4 r; r.v[0] = t.x; r.v[1] = t.y; r.v[2] = t.z; r.v[3] = t.w; return r;
}

__global__ __launch_bounds__(256, 3) void gcl_kernel(const float* __restrict__ f,
                                                     float* __restrict__ ws) {
    __shared__ float cen[3][TH + 2][ROWF];     // staged plane + h-halo rows
    __shared__ float lcol[3][TH], rcol[3][TH]; // w-halo columns (center rows)

    const int tid = threadIdx.x;
    const int tx = tid & 15;
    const int ty = tid >> 4;

    int bid = blockIdx.x;
    const int wb = bid % NWB; bid /= NWB;
    const int hb = bid % NHB; bid /= NHB;
    const int dsg = bid % NDS;
    const int b = bid / NDS;

    const int h0 = hb * TH, w0 = wb * TW, d0 = dsg * DSEG;
    const int h = h0 + ty;
    const int w = w0 + tx * 4;

    const float sy  = (h == 0 || h == HGT - 1) ? 1.0f : 0.5f;
    const float s0w = (w == 0) ? 1.0f : 0.5f;
    const float s3w = (w + 3 == WID - 1) ? 1.0f : 0.5f;

    const bool isTop = (ty == 0), isBot = (ty == TH - 1);
    const bool isL = (tx == 0),  isR = (tx == TW4 - 1);
    const bool isRow = isTop || isBot;
    const bool isCol = isL || isR;
    // clamped halo source coordinates
    const int hrow = isTop ? (h0 > 0 ? h0 - 1 : 0)
                           : (h0 + TH < HGT ? h0 + TH : HGT - 1);
    const int wcol = isL ? (w0 > 0 ? w0 - 1 : 0)
                         : (w0 + TW < WID ? w0 + TW : WID - 1);

    const float* fb = f + b * SB;
    const int pm = (d0 > 0) ? d0 - 1 : 0;

    V4 prev[3], cur[3], nxt[3], nn[3];
    V4 hrowA[3], hrowB[3];
    float hcolA[3], hcolB[3];

    // ---- init: planes d0-1, d0, d0+1 centers; halos for d0 and d0+1 ----
#pragma unroll
    for (int c = 0; c < 3; ++c) {
        const float* pcen = fb + c * SC + h * WID + w;
        prev[c] = ld4(pcen + pm * SD);
        cur[c]  = ld4(pcen + d0 * SD);
        nxt[c]  = ld4(pcen + (d0 + 1) * SD);
    }
    V4 hrow0[3]; float hcol0[3];
    if (isRow) {
#pragma unroll
        for (int c = 0; c < 3; ++c) {
            const float* pr = fb + c * SC + hrow * WID + w;
            hrow0[c] = ld4(pr + d0 * SD);
            hrowA[c] = ld4(pr + (d0 + 1) * SD);
        }
    }
    if (isCol) {
#pragma unroll
        for (int c = 0; c < 3; ++c) {
            const float* pq = fb + c * SC + h * WID + wcol;
            hcol0[c] = pq[d0 * SD];
            hcolA[c] = pq[(d0 + 1) * SD];
        }
    }
    // stage plane d0
#pragma unroll
    for (int c = 0; c < 3; ++c) {
        st4(&cen[c][ty + 1][tx * 4], cur[c]);
        if (isTop) st4(&cen[c][0][tx * 4], hrow0[c]);
        if (isBot) st4(&cen[c][TH + 1][tx * 4], hrow0[c]);
        if (isL) lcol[c][ty] = hcol0[c];
        if (isR) rcol[c][ty] = hcol0[c];
    }
    __syncthreads();

    float local = 0.f;

#pragma unroll
    for (int s = 0; s < DSEG; ++s) {
        const int d = d0 + s;

        // ---- prefetch plane d+2 (consumed in write phase of step s+1) ----
        if (s < DSEG - 1) {
            const int d2 = (d + 2 < DEP) ? d + 2 : DEP - 1;
#pragma unroll
            for (int c = 0; c < 3; ++c)
                nn[c] = ld4(fb + c * SC + d2 * SD + h * WID + w);
            if (isRow) {
#pragma unroll
                for (int c = 0; c < 3; ++c)
                    hrowB[c] = ld4(fb + c * SC + d2 * SD + hrow * WID + w);
            }
            if (isCol) {
#pragma unroll
                for (int c = 0; c < 3; ++c)
                    hcolB[c] = (fb + c * SC + d2 * SD + h * WID)[wcol];
            }
        }

        // ---- compute plane d ----
        const float sx = (d == 0 || d == DEP - 1) ? 1.0f : 0.5f;
        float gx[3][4], gy[3][4], gz[3][4];
#pragma unroll
        for (int c = 0; c < 3; ++c) {
            const V4 hm = ld4s(&cen[c][ty][tx * 4]);      // row h-1 (clamped)
            const V4 hp = ld4s(&cen[c][ty + 2][tx * 4]);  // row h+1 (clamped)
            const float lv = isL ? lcol[c][ty] : cen[c][ty + 1][tx * 4 - 1];
            const float rv = isR ? rcol[c][ty] : cen[c][ty + 1][tx * 4 + 4];
#pragma unroll
            for (int j = 0; j < 4; ++j) {
                gx[c][j] = sx * (nxt[c].v[j] - prev[c].v[j]);
                gy[c][j] = sy * (hp.v[j] - hm.v[j]);
            }
            gz[c][0] = s0w * (cur[c].v[1] - lv);
            gz[c][1] = 0.5f * (cur[c].v[2] - cur[c].v[0]);
            gz[c][2] = 0.5f * (cur[c].v[3] - cur[c].v[1]);
            gz[c][3] = s3w * (rv - cur[c].v[2]);
        }
#pragma unroll
        for (int j = 0; j < 4; ++j) {
            const float dv = gx[0][j] + gy[1][j] + gz[2][j];
            const float cx = gz[1][j] - gy[2][j];
            const float cy = gx[2][j] - gz[0][j];
            const float cz = gy[0][j] - gx[1][j];
            local += dv * dv + sqrtf(cx * cx + cy * cy + cz * cz + EPS_C);
        }

        // ---- stage plane d+1 and rotate ----
        if (s < DSEG - 1) {
            __syncthreads();
#pragma unroll
            for (int c = 0; c < 3; ++c) {
                st4(&cen[c][ty + 1][tx * 4], nxt[c]);
                if (isTop) st4(&cen[c][0][tx * 4], hrowA[c]);
                if (isBot) st4(&cen[c][TH + 1][tx * 4], hrowA[c]);
                if (isL) lcol[c][ty] = hcolA[c];
                if (isR) rcol[c][ty] = hcolA[c];
            }
            __syncthreads();
#pragma unroll
            for (int c = 0; c < 3; ++c) {
                prev[c] = cur[c]; cur[c] = nxt[c]; nxt[c] = nn[c];
                hrowA[c] = hrowB[c]; hcolA[c] = hcolB[c];
            }
        }
    }

    // ---- wave64 butterfly -> cross-wave LDS -> one store per block ----
#pragma unroll
    for (int off = 32; off > 0; off >>= 1)
        local += __shfl_down(local, off, 64);

    __shared__ float wsum[4];
    const int lane = tid & 63;
    const int wv   = tid >> 6;
    if (lane == 0) wsum[wv] = local;
    __syncthreads();
    if (tid == 0)
        ws[blockIdx.x] = wsum[0] + wsum[1] + wsum[2] + wsum[3];
}

__global__ __launch_bounds__(256) void gcl_reduce(const float* __restrict__ ws,
                                                  float* __restrict__ out) {
    float s = 0.f;
    for (int i = threadIdx.x; i < NBLK; i += 256) s += ws[i];
#pragma unroll
    for (int off = 32; off > 0; off >>= 1)
        s += __shfl_down(s, off, 64);
    __shared__ float wsum[4];
    const int lane = threadIdx.x & 63;
    const int wv   = threadIdx.x >> 6;
    if (lane == 0) wsum[wv] = s;
    __syncthreads();
    if (threadIdx.x == 0)
        out[0] = (wsum[0] + wsum[1] + wsum[2] + wsum[3]) * SCALE;
}

extern "C" void kernel_launch(void* const* d_in, const int* in_sizes, int n_in,
                              void* d_out, int out_size, void* d_ws, size_t ws_size,
                              hipStream_t stream) {
    const float* f = (const float*)d_in[0];
    float* out = (float*)d_out;
    float* ws  = (float*)d_ws;   // NBLK*4 = 4.5 KB scratch
    gcl_kernel<<<dim3(NBLK), dim3(256), 0, stream>>>(f, ws);
    gcl_reduce<<<dim3(1), dim3(256), 0, stream>>>(ws, out);
}

// Round 6
// 246.459 us; speedup vs baseline: 1.5540x; 1.5540x over previous
//
#include <hip/hip_runtime.h>

// GradientConsistencyLoss on f[2,3,192,192,192] fp32.
// loss = 0.1 * ( mean(div^2) + mean(sqrt(cx^2+cy^2+cz^2+1e-8)) )
// jnp.gradient semantics: central interior, one-sided edges, unit spacing.
//
// R6 = R5 with the sqrt fixed (__sqrtf is CUDA-only; use
// __builtin_amdgcn_sqrtf -> single v_sqrt_f32).
// R5 theory: R3's register d-pipeline, but only d-centers roll in registers
// (~110 live regs), h/w-neighbor loads issued at top of the same iteration,
// launch_bounds(256,4) -> 128-VGPR cap -> 4 waves/SIMD covers per-iter
// latency. DSEG=12 -> 1.167x d-overlap traffic. No divergent live state.

#define DEP 192
#define HGT 192
#define WID 192
#define NB  2

constexpr int SD = HGT * WID;            // d-stride (floats)
constexpr int SC = DEP * SD;             // channel stride
constexpr int SB = 3 * SC;               // batch stride
constexpr int W4 = WID / 4;              // 48 float4-groups per row
constexpr int DSEG = 12;                 // planes per thread
constexpr int NSEG = DEP / DSEG;         // 16 segments
constexpr int NG   = NB * NSEG * HGT * W4;  // 294,912 threads
constexpr int NBLK = NG / 256;              // 1,152 blocks
constexpr float SCALE = (float)(0.1 / (double)((long long)NB * DEP * HGT * WID));
constexpr float EPS_C = 1e-8f;

struct V4 { float v[4]; };
__device__ __forceinline__ V4 ld4(const float* p) {
    const float4 t = *(const float4*)p;
    V4 r; r.v[0] = t.x; r.v[1] = t.y; r.v[2] = t.z; r.v[3] = t.w; return r;
}

__global__ __launch_bounds__(256, 4) void gcl_kernel(const float* __restrict__ f,
                                                     float* __restrict__ ws) {
    const int g = blockIdx.x * 256 + threadIdx.x;

    int w4 = g % W4;
    int t  = g / W4;
    int h  = t % HGT;
    t /= HGT;
    int ds = t % NSEG;     // block-uniform (36 blocks per segment)
    int b  = t / NSEG;
    const int w  = w4 * 4;
    const int d0 = ds * DSEG;

    const int   hmi = (h > 0) ? h - 1 : 0;
    const int   hpi = (h < HGT - 1) ? h + 1 : HGT - 1;
    const float sy  = (h == 0 || h == HGT - 1) ? 1.0f : 0.5f;
    const int   dhm = (hmi - h) * WID;
    const int   dhp = (hpi - h) * WID;
    const int   loff = (w > 0) ? -1 : 0;
    const int   roff = (w4 < W4 - 1) ? 4 : 3;
    const float s0w = (w == 0) ? 1.0f : 0.5f;
    const float s3w = (w4 == W4 - 1) ? 1.0f : 0.5f;

    const float* base = f + b * SB + h * WID + w;

    // rolling d-pipeline: centers only
    V4 prev[3], cur[3], nxt[3];
    const int pm = (d0 > 0) ? d0 - 1 : 0;
#pragma unroll
    for (int c = 0; c < 3; ++c) {
        const float* pc = base + c * SC;
        prev[c] = ld4(pc + pm * SD);
        cur[c]  = ld4(pc + d0 * SD);
        nxt[c]  = ld4(pc + (d0 + 1) * SD);   // d0+1 <= 181 < 192 always
    }

    float local = 0.f;

#pragma unroll
    for (int s = 0; s < DSEG; ++s) {
        const int d = d0 + s;

        // ---- all loads for this step issued up front ----
        V4 hm[3], hp[3], nn[3];
        float lv[3], rv[3];
#pragma unroll
        for (int c = 0; c < 3; ++c) {
            const float* pd = base + c * SC + d * SD;
            hm[c] = ld4(pd + dhm);
            hp[c] = ld4(pd + dhp);
            lv[c] = pd[loff];
            rv[c] = pd[roff];
        }
        if (s < DSEG - 1) {
            const int d2 = (d + 2 < DEP) ? d + 2 : DEP - 1;  // clamp == edge rule
#pragma unroll
            for (int c = 0; c < 3; ++c)
                nn[c] = ld4(base + c * SC + d2 * SD);
        }

        const float sx = (d == 0 || d == DEP - 1) ? 1.0f : 0.5f;

        // ---- d-direction first: depends only on pipeline registers ----
        float dv[4], cx[4], cy[4], cz[4];
#pragma unroll
        for (int j = 0; j < 4; ++j) {
            dv[j] =  sx * (nxt[0].v[j] - prev[0].v[j]);   // gx(c0) -> +div
            cz[j] = -sx * (nxt[1].v[j] - prev[1].v[j]);   // gx(c1) -> -cz
            cy[j] =  sx * (nxt[2].v[j] - prev[2].v[j]);   // gx(c2) -> +cy
        }
        // ---- w-direction (cur + edge scalars) ----
        {
            float gz0[4], gz1[4], gz2[4];
            gz0[0] = s0w * (cur[0].v[1] - lv[0]);
            gz0[1] = 0.5f * (cur[0].v[2] - cur[0].v[0]);
            gz0[2] = 0.5f * (cur[0].v[3] - cur[0].v[1]);
            gz0[3] = s3w * (rv[0] - cur[0].v[2]);
            gz1[0] = s0w * (cur[1].v[1] - lv[1]);
            gz1[1] = 0.5f * (cur[1].v[2] - cur[1].v[0]);
            gz1[2] = 0.5f * (cur[1].v[3] - cur[1].v[1]);
            gz1[3] = s3w * (rv[1] - cur[1].v[2]);
            gz2[0] = s0w * (cur[2].v[1] - lv[2]);
            gz2[1] = 0.5f * (cur[2].v[2] - cur[2].v[0]);
            gz2[2] = 0.5f * (cur[2].v[3] - cur[2].v[1]);
            gz2[3] = s3w * (rv[2] - cur[2].v[2]);
#pragma unroll
            for (int j = 0; j < 4; ++j) {
                cy[j] -= gz0[j];          // gz(c0) -> -cy
                cx[j]  = gz1[j];          // gz(c1) -> +cx
                dv[j] += gz2[j];          // gz(c2) -> +div
            }
        }
        // ---- h-direction (hm/hp loads) ----
#pragma unroll
        for (int j = 0; j < 4; ++j) {
            cz[j] += sy * (hp[0].v[j] - hm[0].v[j]);      // gy(c0) -> +cz
            dv[j] += sy * (hp[1].v[j] - hm[1].v[j]);      // gy(c1) -> +div
            cx[j] -= sy * (hp[2].v[j] - hm[2].v[j]);      // gy(c2) -> -cx
        }
#pragma unroll
        for (int j = 0; j < 4; ++j)
            local += dv[j] * dv[j] +
                     __builtin_amdgcn_sqrtf(cx[j] * cx[j] + cy[j] * cy[j] +
                                            cz[j] * cz[j] + EPS_C);

        // ---- rotate pipeline ----
        if (s < DSEG - 1) {
#pragma unroll
            for (int c = 0; c < 3; ++c) {
                prev[c] = cur[c]; cur[c] = nxt[c]; nxt[c] = nn[c];
            }
        }
    }

    // ---- wave64 butterfly -> cross-wave LDS -> one store per block ----
#pragma unroll
    for (int off = 32; off > 0; off >>= 1)
        local += __shfl_down(local, off, 64);

    __shared__ float wsum[4];
    const int lane = threadIdx.x & 63;
    const int wv   = threadIdx.x >> 6;
    if (lane == 0) wsum[wv] = local;
    __syncthreads();
    if (threadIdx.x == 0)
        ws[blockIdx.x] = wsum[0] + wsum[1] + wsum[2] + wsum[3];
}

__global__ __launch_bounds__(256) void gcl_reduce(const float* __restrict__ ws,
                                                  float* __restrict__ out) {
    float s = 0.f;
    for (int i = threadIdx.x; i < NBLK; i += 256) s += ws[i];
#pragma unroll
    for (int off = 32; off > 0; off >>= 1)
        s += __shfl_down(s, off, 64);
    __shared__ float wsum[4];
    const int lane = threadIdx.x & 63;
    const int wv   = threadIdx.x >> 6;
    if (lane == 0) wsum[wv] = s;
    __syncthreads();
    if (threadIdx.x == 0)
        out[0] = (wsum[0] + wsum[1] + wsum[2] + wsum[3]) * SCALE;
}

extern "C" void kernel_launch(void* const* d_in, const int* in_sizes, int n_in,
                              void* d_out, int out_size, void* d_ws, size_t ws_size,
                              hipStream_t stream) {
    const float* f = (const float*)d_in[0];
    float* out = (float*)d_out;
    float* ws  = (float*)d_ws;   // NBLK*4 = 4.5 KB scratch
    gcl_kernel<<<dim3(NBLK), dim3(256), 0, stream>>>(f, ws);
    gcl_reduce<<<dim3(1), dim3(256), 0, stream>>>(ws, out);
}